// Round 20
// baseline (137.874 us; speedup 1.0000x reference)
//
#include <hip/hip_runtime.h>

#define S_  2048
#define D_  1024
#define H_  16
#define HD_ 64
#define M_  4096
#define K_  1024
#define NEL 4194304   // B*H*S*HD

typedef short  bf16x8 __attribute__((ext_vector_type(8)));
typedef float  f32x4  __attribute__((ext_vector_type(4)));
typedef float  f32x16 __attribute__((ext_vector_type(16)));
typedef unsigned int   u32;
typedef unsigned int   u32x2 __attribute__((ext_vector_type(2)));
typedef unsigned int   u32x4v __attribute__((ext_vector_type(4)));
typedef unsigned short u16;
typedef unsigned short u16x4 __attribute__((ext_vector_type(4)));

#define MFMA16(c,a,b) (c) = __builtin_amdgcn_mfma_f32_16x16x32_bf16((a),(b),(c),0,0,0)
#define MFMA32(c,a,b) (c) = __builtin_amdgcn_mfma_f32_32x32x16_bf16((a),(b),(c),0,0,0)

// Q pre-scale: 1/sqrt(64) * log2(e) -> softmax in exp2 domain
#define QSCALE 0.18033688011112042f

__device__ __forceinline__ u16 f2bf(float f) {
    union { float f; unsigned u; } v; v.f = f;
    unsigned u = v.u;
    u += 0x7FFFu + ((u >> 16) & 1u);   // RNE
    return (u16)(u >> 16);
}

__device__ __forceinline__ u32 cvtpk(float lo, float hi) {
    u32 r;
    asm("v_cvt_pk_bf16_f32 %0, %1, %2" : "=v"(r) : "v"(lo), "v"(hi));
    return r;
}

// permlane32_swap on DISTINCT registers only (round-11 lesson: aliased
// operands coalesce -> in-place swap -> garbage).  Proven rounds 13-19.
__device__ __forceinline__ u32x2 plswap2(u32 a, u32 b) {
    return __builtin_amdgcn_permlane32_swap(a, b, false, false);
}

__device__ __forceinline__ void gload16(const void* g, void* l) {
    __builtin_amdgcn_global_load_lds(
        (const __attribute__((address_space(1))) unsigned*)g,
        (__attribute__((address_space(3))) unsigned*)l, 16, 0, 0);
}

// ---------------------------------------------------------------------------
// fused converter: blocks [0,2048) convert x f32->bf16; blocks [2048,3072)
// transpose-convert one 64x64 tile of one of the 4 weights (proven r19).
// ---------------------------------------------------------------------------
__global__ __launch_bounds__(256) void cvt_fused(
    const float* __restrict__ x,  u16* __restrict__ xb,
    const float* __restrict__ w0, const float* __restrict__ w1,
    const float* __restrict__ w2, const float* __restrict__ w3,
    u16* __restrict__ Wt)
{
    __shared__ float T[64][65];
    if (blockIdx.x < 2048) {
        const int i = (blockIdx.x * 256 + threadIdx.x) * 8;
        f32x4 a = *(const f32x4*)&x[i];
        f32x4 b = *(const f32x4*)&x[i + 4];
        u16 t[8];
#pragma unroll
        for (int j = 0; j < 4; ++j) { t[j] = f2bf(a[j]); t[4 + j] = f2bf(b[j]); }
        *(bf16x8*)&xb[i] = *(const bf16x8*)t;
        return;
    }
    const int bid = blockIdx.x - 2048;          // 0..1023
    const int z   = bid >> 8;                   // weight select 0..3
    const int kx  = bid & 15, ny = (bid >> 4) & 15;
    const float* W = z == 0 ? w0 : z == 1 ? w1 : z == 2 ? w2 : w3;
    const int k0 = kx * 64, n0 = ny * 64;
    const int r  = threadIdx.x >> 2, c0 = (threadIdx.x & 3) * 16;
#pragma unroll
    for (int j = 0; j < 4; ++j)
        *(f32x4*)&T[r][c0 + j * 4] = *(const f32x4*)&W[(size_t)(k0 + r) * D_ + n0 + c0 + j * 4];
    __syncthreads();
    u16 tmp[16];
#pragma unroll
    for (int j = 0; j < 16; ++j) tmp[j] = f2bf(T[c0 + j][r]);
    u16* dst = Wt + ((size_t)z * 1024 + n0 + r) * K_ + k0 + c0;
    *(bf16x8*)dst       = *(const bf16x8*)tmp;
    *(bf16x8*)(dst + 8) = *(const bf16x8*)(tmp + 8);
}

// ---------------------------------------------------------------------------
// m97-style GEMM.  Biases passed directly; MODE 0 selects bq/bk/bv by n>>10
// (proven rounds 6-19).  ROUND 20: O-proj now uses BM=128 too (staging per
// output 0.75 -> 0.5 tile-stages; m93 ladder: 64-tile ~343 TF vs 128 ~912).
// ---------------------------------------------------------------------------
template <int BM, int MODE>
__global__ __launch_bounds__(256) void gemm2(
    const u16* __restrict__ A, const u16* __restrict__ Bt,
    const float* __restrict__ b0, const float* __restrict__ b1,
    const float* __restrict__ b2, void* __restrict__ Out)
{
    __shared__ u16 As[BM * 32];
    __shared__ u16 Bs[128 * 32];
    const int tid = threadIdx.x, lane = tid & 63, wid = tid >> 6;
    const int lr = lane & 15, lg = lane >> 4;
    const int n0 = blockIdx.x * 128, m0 = blockIdx.y * BM;
    const int wm = (wid >> 1) * (BM / 2), wn = (wid & 1) * 64;
    const int lrow = lane >> 2, lch = lane & 3;

    f32x4 acc[BM / 32][4] = {};

    for (int k0 = 0; k0 < K_; k0 += 32) {
        __syncthreads();
#pragma unroll
        for (int t = 0; t < BM / 64; ++t) {
            const int row = wid * (BM / 4) + t * 16 + lrow;
            gload16(A + (size_t)(m0 + row) * K_ + k0 + lch * 8,
                    (u16*)As + row * 32 + lch * 8);
        }
#pragma unroll
        for (int t = 0; t < 2; ++t) {
            const int row = wid * 32 + t * 16 + lrow;
            gload16(Bt + (size_t)(n0 + row) * K_ + k0 + lch * 8,
                    (u16*)Bs + row * 32 + lch * 8);
        }
        __syncthreads();

        bf16x8 af[BM / 32], bf[4];
#pragma unroll
        for (int i = 0; i < BM / 32; ++i)
            af[i] = *(const bf16x8*)&As[(wm + i * 16 + lr) * 32 + lg * 8];
#pragma unroll
        for (int j = 0; j < 4; ++j)
            bf[j] = *(const bf16x8*)&Bs[(wn + j * 16 + lr) * 32 + lg * 8];
#pragma unroll
        for (int i = 0; i < BM / 32; ++i)
#pragma unroll
            for (int j = 0; j < 4; ++j) MFMA16(acc[i][j], af[i], bf[j]);
    }

#pragma unroll
    for (int i = 0; i < BM / 32; ++i) {
#pragma unroll
        for (int j = 0; j < 4; ++j) {
            const int n = n0 + wn + j * 16 + lr;
            const int m = m0 + wm + i * 16 + lg * 4;
            if constexpr (MODE == 0) {
                const int which = n >> 10, nn = n & 1023;
                const float* bp = which == 0 ? b0 : which == 1 ? b1 : b2;
                const float bv = bp[nn];
                u16* qkv = (u16*)Out;
                const int h = nn >> 6, hd = nn & 63;
                const int b = m >> 11, s = m & 2047;
                if (which == 2) {                         // V: [bh][hd][s]
                    u16x4 pk;
#pragma unroll
                    for (int r4 = 0; r4 < 4; ++r4) pk[r4] = f2bf(acc[i][j][r4] + bv);
                    *(u16x4*)&qkv[(size_t)2 * NEL +
                                  ((size_t)(b * H_ + h) * HD_ + hd) * S_ + s] = pk;
                } else {                                  // Q/K: [bh][s][hd]
                    const float sc = (which == 0) ? QSCALE : 1.0f;
                    const size_t bas = (size_t)which * NEL + (size_t)(b * H_ + h) * S_ * HD_;
#pragma unroll
                    for (int r4 = 0; r4 < 4; ++r4)
                        qkv[bas + (size_t)(s + r4) * HD_ + hd] =
                            f2bf((acc[i][j][r4] + bv) * sc);
                }
            } else {
                const float bv = b0[n];
                float* o = (float*)Out;
#pragma unroll
                for (int r4 = 0; r4 < 4; ++r4)
                    o[(size_t)(m + r4) * D_ + n] = acc[i][j][r4] + bv;
            }
        }
    }
}

// ---------------------------------------------------------------------------
// attn16 (round-14 datapath, measured best 58.5-58.7us across r14/r19).
// Per-wave LDS staging of K/V via coalesced global_load_lds, swapped-QK^T,
// permlane A-frags, in-block 2-wave merge.  Rounds 15-18 proved null/negative:
// prefetch (TLP hides vmcnt), pairing (not tail-bound), VGPR trim (not
// reg-bound), shared 4-wave staging (barrier lockstep).  Local optimum.
// C/D layout: col=lane&31, row=(r&3)+8(r>>2)+4*(lane>>5)  [m74/m101].
// ---------------------------------------------------------------------------
__global__ __launch_bounds__(128) void attn16(
    const u16* __restrict__ Q, const u16* __restrict__ K,
    const u16* __restrict__ Vt, u16* __restrict__ CTX)
{
    __shared__ __align__(16) char SMEM[32768];   // [wave][K 8KB | V 8KB]

    const int tid  = threadIdx.x;
    const int lane = tid & 63, wv = tid >> 6;
    const int lo = lane & 31, hi = lane >> 5;
    const int idx = blockIdx.x;
    const int bh  = idx & 31;
    const int qb  = 63 - (idx >> 5);       // heavy q-blocks first
    const int wq0 = qb * 32;
    const size_t base  = (size_t)bh * S_ * HD_;   // Q,K: [bh][s][hd]
    const size_t vbase = (size_t)bh * HD_ * S_;   // Vt:  [bh][hd][s]

    char* Kw = SMEM + wv * 16384;
    char* Vw = Kw + 8192;
    // merge buffers alias wave-1's staging region (written only post-loop)
    float (*OB)[33] = (float (*)[33])(SMEM + 16384);
    float* MBp = (float*)(SMEM + 16384 + 8448);
    float* LBp = MBp + 64;

    // permlane return-order probe (wave-uniform)
    bool flip;
    {
        u32 pa = hi ? 10u : 20u;
        u32 pb = hi ? 30u : 40u;
        u32x2 pr = plswap2(pa, pb);
        flip = (pr[0] == 10u) || (pr[0] == 30u);
    }

    // staging lane decomposition: 8 lanes/row, 16B chunks, swizzled source
    const int r8  = lane >> 3;            // row within 8-row group (= row&7)
    const int csw = (lane & 7) ^ r8;      // source chunk (XOR swizzle)
    const int swz = lo & 7;               // reader swizzle key

    // Q as B-fragment: lane holds col q=lo, k = 16*ks + 8*hi + j
    bf16x8 qf[4];
#pragma unroll
    for (int ks = 0; ks < 4; ++ks)
        qf[ks] = *(const bf16x8*)&Q[base + (size_t)(wq0 + lo) * HD_ + ks * 16 + hi * 8];

    f32x16 acc[2] = {};
    float m_ = -1e30f, l_ = 0.f;
    const int nt = (wq0 >> 6) + 1;

    for (int t = wv; t < nt; t += 2) {
        const int kv0 = t * 64;
        const bool sub1 = (kv0 + 32 <= wq0 + 31);

        // ---- stage K + V via coalesced global_load_lds (r14, proven) ----
        {
            const u16* kSrc = K  + base  + (size_t)(kv0 + r8) * HD_ + csw * 8;
            const u16* vSrc = Vt + vbase + (size_t)r8 * S_ + kv0 + csw * 8;
            char* kDst = Kw + (lane << 4);
            char* vDst = Vw + (lane << 4);
            const int ni = sub1 ? 8 : 4;
            for (int i = 0; i < ni; ++i)
                gload16(kSrc + (size_t)(i * 8) * HD_, kDst + i * 1024);
#pragma unroll
            for (int i = 0; i < 8; ++i)
                gload16(vSrc + (size_t)(i * 8) * S_, vDst + i * 1024);
            asm volatile("s_waitcnt vmcnt(0)" ::: "memory");
        }

        // ---- QK^T (S^T): A = K rows (from LDS), B = Q ----
        f32x16 cT[2];
#pragma unroll
        for (int i = 0; i < 16; ++i) { cT[0][i] = 0.f; cT[1][i] = 0.f; }
        __builtin_amdgcn_s_setprio(1);
#pragma unroll
        for (int ks = 0; ks < 4; ++ks) {
            bf16x8 kf = *(const bf16x8*)(Kw + (lo << 7) + (((2 * ks + hi) ^ swz) << 4));
            MFMA32(cT[0], kf, qf[ks]);
        }
        if (sub1) {
#pragma unroll
            for (int ks = 0; ks < 4; ++ks) {
                bf16x8 kf = *(const bf16x8*)(Kw + ((32 + lo) << 7) + (((2 * ks + hi) ^ swz) << 4));
                MFMA32(cT[1], kf, qf[ks]);
            }
        }
        __builtin_amdgcn_s_setprio(0);

        // ---- V B-frags read early from LDS (hide under softmax) ----
        bf16x8 vf[2][4];
#pragma unroll
        for (int dt = 0; dt < 2; ++dt)
#pragma unroll
            for (int ks = 0; ks < 4; ++ks)
                if (ks < 2 || sub1)
                    vf[dt][ks] = *(const bf16x8*)(Vw + ((dt * 32 + lo) << 7) +
                                                  (((2 * ks + hi) ^ swz) << 4));

        // ---- causal mask (diagonal passes only) ----
        if (kv0 + 63 > wq0) {
            const int qg = wq0 + lo;
#pragma unroll
            for (int tt = 0; tt < 2; ++tt)
#pragma unroll
                for (int r = 0; r < 16; ++r) {
                    const int kvg = kv0 + tt * 32 + (r & 3) + 8 * (r >> 2) + 4 * hi;
                    if (kvg > qg) cT[tt][r] = -1e9f;
                }
        }

        // ---- row max: in-register tree + 1 cross-lane (proven shfl) ----
        float m8[8];
#pragma unroll
        for (int i = 0; i < 8; ++i)
            m8[i] = fmaxf(fmaxf(cT[0][i], cT[0][i + 8]), fmaxf(cT[1][i], cT[1][i + 8]));
        float mx = fmaxf(fmaxf(fmaxf(m8[0], m8[1]), fmaxf(m8[2], m8[3])),
                         fmaxf(fmaxf(m8[4], m8[5]), fmaxf(m8[6], m8[7])));
        mx = fmaxf(mx, __shfl_xor(mx, 32));

        // ---- defer-max (T13, exp2 domain: 11.5 = 8*log2e) ----
        if (!__all(mx <= m_ + 11.5f)) {
            const float mn = fmaxf(m_, mx);
            const float al = exp2f(m_ - mn);
            m_ = mn; l_ *= al;
            float alr[16];
#pragma unroll
            for (int r = 0; r < 16; ++r)
                alr[r] = __shfl(al, (r & 3) + 8 * (r >> 2) + 4 * hi);
#pragma unroll
            for (int r = 0; r < 16; ++r) { acc[0][r] *= alr[r]; acc[1][r] *= alr[r]; }
        }

        // ---- P = exp2(S - m), lane-local sum + 1 cross-lane ----
#pragma unroll
        for (int i = 0; i < 16; ++i) {
            cT[0][i] = exp2f(cT[0][i] - m_);
            cT[1][i] = exp2f(cT[1][i] - m_);
        }
        float s8[8];
#pragma unroll
        for (int i = 0; i < 8; ++i)
            s8[i] = (cT[0][i] + cT[0][i + 8]) + (cT[1][i] + cT[1][i + 8]);
        float ssum = ((s8[0] + s8[1]) + (s8[2] + s8[3])) +
                     ((s8[4] + s8[5]) + (s8[6] + s8[7]));
        ssum += __shfl_xor(ssum, 32);
        l_ += ssum;

        // ---- pack P to bf16 pairs ----
        u32 pk[2][8];
#pragma unroll
        for (int tt = 0; tt < 2; ++tt)
#pragma unroll
            for (int w = 0; w < 8; ++w)
                pk[tt][w] = cvtpk(cT[tt][2 * w], cT[tt][2 * w + 1]);

        // ---- build PV A-frags via permlane32_swap (proven r13-19); PV ----
#pragma unroll
        for (int ks = 0; ks < 4; ++ks) {
            if (ks < 2 || sub1) {
                const int tt = ks >> 1;
                const int o4 = (ks & 1) * 4;
                u32x2 s0 = plswap2(pk[tt][o4 + 0], pk[tt][o4 + 2]);
                u32x2 s1 = plswap2(pk[tt][o4 + 1], pk[tt][o4 + 3]);
                u32x4v v;
                v.x = flip ? s0[1] : s0[0];
                v.y = flip ? s1[1] : s1[0];
                v.z = flip ? s0[0] : s0[1];
                v.w = flip ? s1[0] : s1[1];
                const bf16x8 af = __builtin_bit_cast(bf16x8, v);
                __builtin_amdgcn_s_setprio(1);
                MFMA32(acc[0], af, vf[0][ks]);
                MFMA32(acc[1], af, vf[1][ks]);
                __builtin_amdgcn_s_setprio(0);
            }
        }
    }

    // ---- in-block merge: wave1 publishes (into its own dead LDS), wave0
    //      combines + stores ----
    if (wv == 1) {
#pragma unroll
        for (int r = 0; r < 16; ++r) {
            OB[lane][r]      = acc[0][r];
            OB[lane][16 + r] = acc[1][r];
        }
        MBp[lane] = m_;
        LBp[lane] = l_;
    }
    __syncthreads();
    if (wv != 0) return;

    const float m1 = MBp[lane], l1 = LBp[lane];
    const float mM = fmaxf(m_, m1);
    const float a0 = exp2f(m_ - mM), a1 = exp2f(m1 - mM);
    l_ = l_ * a0 + l1 * a1;
    float a0r[16], a1r[16];
#pragma unroll
    for (int r = 0; r < 16; ++r) {
        const int rq = (r & 3) + 8 * (r >> 2) + 4 * hi;
        a0r[r] = __shfl(a0, rq);
        a1r[r] = __shfl(a1, rq);
    }
#pragma unroll
    for (int r = 0; r < 16; ++r) {
        acc[0][r] = acc[0][r] * a0r[r] + OB[lane][r]      * a1r[r];
        acc[1][r] = acc[1][r] * a0r[r] + OB[lane][16 + r] * a1r[r];
    }

    const float linv = 1.0f / l_;
    float lrr[16];
#pragma unroll
    for (int r = 0; r < 16; ++r)
        lrr[r] = __shfl(linv, (r & 3) + 8 * (r >> 2) + 4 * hi);
    const int b = bh >> 4, h = bh & 15;
#pragma unroll
    for (int r = 0; r < 16; ++r) {
        const int q = wq0 + (r & 3) + 8 * (r >> 2) + 4 * hi;
        u16* o = &CTX[(size_t)(b * S_ + q) * D_ + h * HD_ + lo];
        o[0]  = f2bf(acc[0][r] * lrr[r]);
        o[32] = f2bf(acc[1][r] * lrr[r]);
    }
}

// ---------------------------------------------------------------------------
extern "C" void kernel_launch(void* const* d_in, const int* in_sizes, int n_in,
                              void* d_out, int out_size, void* d_ws, size_t ws_size,
                              hipStream_t stream)
{
    const float* x  = (const float*)d_in[0];
    const float* wq = (const float*)d_in[1];
    const float* bq = (const float*)d_in[2];
    const float* wk = (const float*)d_in[3];
    const float* bk = (const float*)d_in[4];
    const float* wv = (const float*)d_in[5];
    const float* bv = (const float*)d_in[6];
    const float* wo = (const float*)d_in[7];
    const float* bo = (const float*)d_in[8];

    char* ws = (char*)d_ws;
    u16*   xb    = (u16*)ws;                                  // 8 MB (reused as ctx)
    u16*   WtAll = (u16*)(ws + (size_t)8  * 1024 * 1024);     // 8 MB, rows q|k|v|o
    u16*   qkv   = (u16*)(ws + (size_t)16 * 1024 * 1024);     // 24 MB: q | k | vT
    u16*   ctx   = xb;

    cvt_fused<<<3072, 256, 0, stream>>>(x, xb, wq, wk, wv, wo, WtAll);

    gemm2<128, 0><<<dim3(24, 32), 256, 0, stream>>>(xb, WtAll, bq, bk, bv, qkv);

    attn16<<<dim3(2048), 128, 0, stream>>>(qkv, qkv + NEL, qkv + 2 * (size_t)NEL, ctx);

    // O-projection: BM=128 tile (r20 change) — 256 blocks, staging/output
    // 0.75 -> 0.5 tile-stages, same proven codepath as the QKV GEMM.
    gemm2<128, 1><<<dim3(8, 32), 256, 0, stream>>>(ctx, WtAll + (size_t)3072 * K_,
                                                   bo, bo, bo, d_out);
}

// Round 21
// 132.121 us; speedup vs baseline: 1.0435x; 1.0435x over previous
//
#include <hip/hip_runtime.h>

#define S_  2048
#define D_  1024
#define H_  16
#define HD_ 64
#define M_  4096
#define K_  1024
#define NEL 4194304   // B*H*S*HD

typedef short  bf16x8 __attribute__((ext_vector_type(8)));
typedef float  f32x4  __attribute__((ext_vector_type(4)));
typedef float  f32x16 __attribute__((ext_vector_type(16)));
typedef unsigned int   u32;
typedef unsigned int   u32x2 __attribute__((ext_vector_type(2)));
typedef unsigned int   u32x4v __attribute__((ext_vector_type(4)));
typedef unsigned short u16;
typedef unsigned short u16x4 __attribute__((ext_vector_type(4)));

#define MFMA16(c,a,b) (c) = __builtin_amdgcn_mfma_f32_16x16x32_bf16((a),(b),(c),0,0,0)
#define MFMA32(c,a,b) (c) = __builtin_amdgcn_mfma_f32_32x32x16_bf16((a),(b),(c),0,0,0)

// Q pre-scale: 1/sqrt(64) * log2(e) -> softmax in exp2 domain
#define QSCALE 0.18033688011112042f

__device__ __forceinline__ u16 f2bf(float f) {
    union { float f; unsigned u; } v; v.f = f;
    unsigned u = v.u;
    u += 0x7FFFu + ((u >> 16) & 1u);   // RNE
    return (u16)(u >> 16);
}

__device__ __forceinline__ u32 cvtpk(float lo, float hi) {
    u32 r;
    asm("v_cvt_pk_bf16_f32 %0, %1, %2" : "=v"(r) : "v"(lo), "v"(hi));
    return r;
}

// permlane32_swap on DISTINCT registers only (round-11 lesson: aliased
// operands coalesce -> in-place swap -> garbage).  Proven rounds 13-20.
__device__ __forceinline__ u32x2 plswap2(u32 a, u32 b) {
    return __builtin_amdgcn_permlane32_swap(a, b, false, false);
}

__device__ __forceinline__ void gload16(const void* g, void* l) {
    __builtin_amdgcn_global_load_lds(
        (const __attribute__((address_space(1))) unsigned*)g,
        (__attribute__((address_space(3))) unsigned*)l, 16, 0, 0);
}

// ---------------------------------------------------------------------------
// fused converter: blocks [0,2048) convert x f32->bf16; blocks [2048,3072)
// transpose-convert one 64x64 tile of one of the 4 weights (proven r19).
// ---------------------------------------------------------------------------
__global__ __launch_bounds__(256) void cvt_fused(
    const float* __restrict__ x,  u16* __restrict__ xb,
    const float* __restrict__ w0, const float* __restrict__ w1,
    const float* __restrict__ w2, const float* __restrict__ w3,
    u16* __restrict__ Wt)
{
    __shared__ float T[64][65];
    if (blockIdx.x < 2048) {
        const int i = (blockIdx.x * 256 + threadIdx.x) * 8;
        f32x4 a = *(const f32x4*)&x[i];
        f32x4 b = *(const f32x4*)&x[i + 4];
        u16 t[8];
#pragma unroll
        for (int j = 0; j < 4; ++j) { t[j] = f2bf(a[j]); t[4 + j] = f2bf(b[j]); }
        *(bf16x8*)&xb[i] = *(const bf16x8*)t;
        return;
    }
    const int bid = blockIdx.x - 2048;          // 0..1023
    const int z   = bid >> 8;                   // weight select 0..3
    const int kx  = bid & 15, ny = (bid >> 4) & 15;
    const float* W = z == 0 ? w0 : z == 1 ? w1 : z == 2 ? w2 : w3;
    const int k0 = kx * 64, n0 = ny * 64;
    const int r  = threadIdx.x >> 2, c0 = (threadIdx.x & 3) * 16;
#pragma unroll
    for (int j = 0; j < 4; ++j)
        *(f32x4*)&T[r][c0 + j * 4] = *(const f32x4*)&W[(size_t)(k0 + r) * D_ + n0 + c0 + j * 4];
    __syncthreads();
    u16 tmp[16];
#pragma unroll
    for (int j = 0; j < 16; ++j) tmp[j] = f2bf(T[c0 + j][r]);
    u16* dst = Wt + ((size_t)z * 1024 + n0 + r) * K_ + k0 + c0;
    *(bf16x8*)dst       = *(const bf16x8*)tmp;
    *(bf16x8*)(dst + 8) = *(const bf16x8*)(tmp + 8);
}

// ---------------------------------------------------------------------------
// m97-style GEMM.  Biases passed directly; MODE 0 selects bq/bk/bv by n>>10
// (proven rounds 6-20).  O-proj uses BM=64 (r20 falsified BM=128 there:
// 256 blocks = 1/CU loses cross-block barrier hiding, +5.5us).
// ---------------------------------------------------------------------------
template <int BM, int MODE>
__global__ __launch_bounds__(256) void gemm2(
    const u16* __restrict__ A, const u16* __restrict__ Bt,
    const float* __restrict__ b0, const float* __restrict__ b1,
    const float* __restrict__ b2, void* __restrict__ Out)
{
    __shared__ u16 As[BM * 32];
    __shared__ u16 Bs[128 * 32];
    const int tid = threadIdx.x, lane = tid & 63, wid = tid >> 6;
    const int lr = lane & 15, lg = lane >> 4;
    const int n0 = blockIdx.x * 128, m0 = blockIdx.y * BM;
    const int wm = (wid >> 1) * (BM / 2), wn = (wid & 1) * 64;
    const int lrow = lane >> 2, lch = lane & 3;

    f32x4 acc[BM / 32][4] = {};

    for (int k0 = 0; k0 < K_; k0 += 32) {
        __syncthreads();
#pragma unroll
        for (int t = 0; t < BM / 64; ++t) {
            const int row = wid * (BM / 4) + t * 16 + lrow;
            gload16(A + (size_t)(m0 + row) * K_ + k0 + lch * 8,
                    (u16*)As + row * 32 + lch * 8);
        }
#pragma unroll
        for (int t = 0; t < 2; ++t) {
            const int row = wid * 32 + t * 16 + lrow;
            gload16(Bt + (size_t)(n0 + row) * K_ + k0 + lch * 8,
                    (u16*)Bs + row * 32 + lch * 8);
        }
        __syncthreads();

        bf16x8 af[BM / 32], bf[4];
#pragma unroll
        for (int i = 0; i < BM / 32; ++i)
            af[i] = *(const bf16x8*)&As[(wm + i * 16 + lr) * 32 + lg * 8];
#pragma unroll
        for (int j = 0; j < 4; ++j)
            bf[j] = *(const bf16x8*)&Bs[(wn + j * 16 + lr) * 32 + lg * 8];
#pragma unroll
        for (int i = 0; i < BM / 32; ++i)
#pragma unroll
            for (int j = 0; j < 4; ++j) MFMA16(acc[i][j], af[i], bf[j]);
    }

#pragma unroll
    for (int i = 0; i < BM / 32; ++i) {
#pragma unroll
        for (int j = 0; j < 4; ++j) {
            const int n = n0 + wn + j * 16 + lr;
            const int m = m0 + wm + i * 16 + lg * 4;
            if constexpr (MODE == 0) {
                const int which = n >> 10, nn = n & 1023;
                const float* bp = which == 0 ? b0 : which == 1 ? b1 : b2;
                const float bv = bp[nn];
                u16* qkv = (u16*)Out;
                const int h = nn >> 6, hd = nn & 63;
                const int b = m >> 11, s = m & 2047;
                if (which == 2) {                         // V: [bh][hd][s]
                    u16x4 pk;
#pragma unroll
                    for (int r4 = 0; r4 < 4; ++r4) pk[r4] = f2bf(acc[i][j][r4] + bv);
                    *(u16x4*)&qkv[(size_t)2 * NEL +
                                  ((size_t)(b * H_ + h) * HD_ + hd) * S_ + s] = pk;
                } else {                                  // Q/K: [bh][s][hd]
                    const float sc = (which == 0) ? QSCALE : 1.0f;
                    const size_t bas = (size_t)which * NEL + (size_t)(b * H_ + h) * S_ * HD_;
#pragma unroll
                    for (int r4 = 0; r4 < 4; ++r4)
                        qkv[bas + (size_t)(s + r4) * HD_ + hd] =
                            f2bf((acc[i][j][r4] + bv) * sc);
                }
            } else {
                const float bv = b0[n];
                float* o = (float*)Out;
#pragma unroll
                for (int r4 = 0; r4 < 4; ++r4)
                    o[(size_t)(m + r4) * D_ + n] = acc[i][j][r4] + bv;
            }
        }
    }
}

// ---------------------------------------------------------------------------
// attn16 (round-14 datapath, measured best 58.2-58.7us across r14/r19/r20).
// Per-wave LDS staging of K/V via coalesced global_load_lds, swapped-QK^T,
// permlane A-frags, in-block 2-wave merge.  Rounds 15-18 proved null/negative:
// prefetch (TLP hides vmcnt), pairing (not tail-bound), VGPR trim (not
// reg-bound), shared 4-wave staging (barrier lockstep).  Local optimum.
// C/D layout: col=lane&31, row=(r&3)+8(r>>2)+4*(lane>>5)  [m74/m101].
// ---------------------------------------------------------------------------
__global__ __launch_bounds__(128) void attn16(
    const u16* __restrict__ Q, const u16* __restrict__ K,
    const u16* __restrict__ Vt, u16* __restrict__ CTX)
{
    __shared__ __align__(16) char SMEM[32768];   // [wave][K 8KB | V 8KB]

    const int tid  = threadIdx.x;
    const int lane = tid & 63, wv = tid >> 6;
    const int lo = lane & 31, hi = lane >> 5;
    const int idx = blockIdx.x;
    const int bh  = idx & 31;
    const int qb  = 63 - (idx >> 5);       // heavy q-blocks first
    const int wq0 = qb * 32;
    const size_t base  = (size_t)bh * S_ * HD_;   // Q,K: [bh][s][hd]
    const size_t vbase = (size_t)bh * HD_ * S_;   // Vt:  [bh][hd][s]

    char* Kw = SMEM + wv * 16384;
    char* Vw = Kw + 8192;
    // merge buffers alias wave-1's staging region (written only post-loop)
    float (*OB)[33] = (float (*)[33])(SMEM + 16384);
    float* MBp = (float*)(SMEM + 16384 + 8448);
    float* LBp = MBp + 64;

    // permlane return-order probe (wave-uniform)
    bool flip;
    {
        u32 pa = hi ? 10u : 20u;
        u32 pb = hi ? 30u : 40u;
        u32x2 pr = plswap2(pa, pb);
        flip = (pr[0] == 10u) || (pr[0] == 30u);
    }

    // staging lane decomposition: 8 lanes/row, 16B chunks, swizzled source
    const int r8  = lane >> 3;            // row within 8-row group (= row&7)
    const int csw = (lane & 7) ^ r8;      // source chunk (XOR swizzle)
    const int swz = lo & 7;               // reader swizzle key

    // Q as B-fragment: lane holds col q=lo, k = 16*ks + 8*hi + j
    bf16x8 qf[4];
#pragma unroll
    for (int ks = 0; ks < 4; ++ks)
        qf[ks] = *(const bf16x8*)&Q[base + (size_t)(wq0 + lo) * HD_ + ks * 16 + hi * 8];

    f32x16 acc[2] = {};
    float m_ = -1e30f, l_ = 0.f;
    const int nt = (wq0 >> 6) + 1;

    for (int t = wv; t < nt; t += 2) {
        const int kv0 = t * 64;
        const bool sub1 = (kv0 + 32 <= wq0 + 31);

        // ---- stage K + V via coalesced global_load_lds (r14, proven) ----
        {
            const u16* kSrc = K  + base  + (size_t)(kv0 + r8) * HD_ + csw * 8;
            const u16* vSrc = Vt + vbase + (size_t)r8 * S_ + kv0 + csw * 8;
            char* kDst = Kw + (lane << 4);
            char* vDst = Vw + (lane << 4);
            const int ni = sub1 ? 8 : 4;
            for (int i = 0; i < ni; ++i)
                gload16(kSrc + (size_t)(i * 8) * HD_, kDst + i * 1024);
#pragma unroll
            for (int i = 0; i < 8; ++i)
                gload16(vSrc + (size_t)(i * 8) * S_, vDst + i * 1024);
            asm volatile("s_waitcnt vmcnt(0)" ::: "memory");
        }

        // ---- QK^T (S^T): A = K rows (from LDS), B = Q ----
        f32x16 cT[2];
#pragma unroll
        for (int i = 0; i < 16; ++i) { cT[0][i] = 0.f; cT[1][i] = 0.f; }
        __builtin_amdgcn_s_setprio(1);
#pragma unroll
        for (int ks = 0; ks < 4; ++ks) {
            bf16x8 kf = *(const bf16x8*)(Kw + (lo << 7) + (((2 * ks + hi) ^ swz) << 4));
            MFMA32(cT[0], kf, qf[ks]);
        }
        if (sub1) {
#pragma unroll
            for (int ks = 0; ks < 4; ++ks) {
                bf16x8 kf = *(const bf16x8*)(Kw + ((32 + lo) << 7) + (((2 * ks + hi) ^ swz) << 4));
                MFMA32(cT[1], kf, qf[ks]);
            }
        }
        __builtin_amdgcn_s_setprio(0);

        // ---- V B-frags read early from LDS (hide under softmax) ----
        bf16x8 vf[2][4];
#pragma unroll
        for (int dt = 0; dt < 2; ++dt)
#pragma unroll
            for (int ks = 0; ks < 4; ++ks)
                if (ks < 2 || sub1)
                    vf[dt][ks] = *(const bf16x8*)(Vw + ((dt * 32 + lo) << 7) +
                                                  (((2 * ks + hi) ^ swz) << 4));

        // ---- causal mask (diagonal passes only) ----
        if (kv0 + 63 > wq0) {
            const int qg = wq0 + lo;
#pragma unroll
            for (int tt = 0; tt < 2; ++tt)
#pragma unroll
                for (int r = 0; r < 16; ++r) {
                    const int kvg = kv0 + tt * 32 + (r & 3) + 8 * (r >> 2) + 4 * hi;
                    if (kvg > qg) cT[tt][r] = -1e9f;
                }
        }

        // ---- row max: in-register tree + 1 cross-lane (proven shfl) ----
        float m8[8];
#pragma unroll
        for (int i = 0; i < 8; ++i)
            m8[i] = fmaxf(fmaxf(cT[0][i], cT[0][i + 8]), fmaxf(cT[1][i], cT[1][i + 8]));
        float mx = fmaxf(fmaxf(fmaxf(m8[0], m8[1]), fmaxf(m8[2], m8[3])),
                         fmaxf(fmaxf(m8[4], m8[5]), fmaxf(m8[6], m8[7])));
        mx = fmaxf(mx, __shfl_xor(mx, 32));

        // ---- defer-max (T13, exp2 domain: 11.5 = 8*log2e) ----
        if (!__all(mx <= m_ + 11.5f)) {
            const float mn = fmaxf(m_, mx);
            const float al = exp2f(m_ - mn);
            m_ = mn; l_ *= al;
            float alr[16];
#pragma unroll
            for (int r = 0; r < 16; ++r)
                alr[r] = __shfl(al, (r & 3) + 8 * (r >> 2) + 4 * hi);
#pragma unroll
            for (int r = 0; r < 16; ++r) { acc[0][r] *= alr[r]; acc[1][r] *= alr[r]; }
        }

        // ---- P = exp2(S - m), lane-local sum + 1 cross-lane ----
#pragma unroll
        for (int i = 0; i < 16; ++i) {
            cT[0][i] = exp2f(cT[0][i] - m_);
            cT[1][i] = exp2f(cT[1][i] - m_);
        }
        float s8[8];
#pragma unroll
        for (int i = 0; i < 8; ++i)
            s8[i] = (cT[0][i] + cT[0][i + 8]) + (cT[1][i] + cT[1][i + 8]);
        float ssum = ((s8[0] + s8[1]) + (s8[2] + s8[3])) +
                     ((s8[4] + s8[5]) + (s8[6] + s8[7]));
        ssum += __shfl_xor(ssum, 32);
        l_ += ssum;

        // ---- pack P to bf16 pairs ----
        u32 pk[2][8];
#pragma unroll
        for (int tt = 0; tt < 2; ++tt)
#pragma unroll
            for (int w = 0; w < 8; ++w)
                pk[tt][w] = cvtpk(cT[tt][2 * w], cT[tt][2 * w + 1]);

        // ---- build PV A-frags via permlane32_swap (proven r13-20); PV ----
#pragma unroll
        for (int ks = 0; ks < 4; ++ks) {
            if (ks < 2 || sub1) {
                const int tt = ks >> 1;
                const int o4 = (ks & 1) * 4;
                u32x2 s0 = plswap2(pk[tt][o4 + 0], pk[tt][o4 + 2]);
                u32x2 s1 = plswap2(pk[tt][o4 + 1], pk[tt][o4 + 3]);
                u32x4v v;
                v.x = flip ? s0[1] : s0[0];
                v.y = flip ? s1[1] : s1[0];
                v.z = flip ? s0[0] : s0[1];
                v.w = flip ? s1[0] : s1[1];
                const bf16x8 af = __builtin_bit_cast(bf16x8, v);
                __builtin_amdgcn_s_setprio(1);
                MFMA32(acc[0], af, vf[0][ks]);
                MFMA32(acc[1], af, vf[1][ks]);
                __builtin_amdgcn_s_setprio(0);
            }
        }
    }

    // ---- in-block merge: wave1 publishes (into its own dead LDS), wave0
    //      combines + stores ----
    if (wv == 1) {
#pragma unroll
        for (int r = 0; r < 16; ++r) {
            OB[lane][r]      = acc[0][r];
            OB[lane][16 + r] = acc[1][r];
        }
        MBp[lane] = m_;
        LBp[lane] = l_;
    }
    __syncthreads();
    if (wv != 0) return;

    const float m1 = MBp[lane], l1 = LBp[lane];
    const float mM = fmaxf(m_, m1);
    const float a0 = exp2f(m_ - mM), a1 = exp2f(m1 - mM);
    l_ = l_ * a0 + l1 * a1;
    float a0r[16], a1r[16];
#pragma unroll
    for (int r = 0; r < 16; ++r) {
        const int rq = (r & 3) + 8 * (r >> 2) + 4 * hi;
        a0r[r] = __shfl(a0, rq);
        a1r[r] = __shfl(a1, rq);
    }
#pragma unroll
    for (int r = 0; r < 16; ++r) {
        acc[0][r] = acc[0][r] * a0r[r] + OB[lane][r]      * a1r[r];
        acc[1][r] = acc[1][r] * a0r[r] + OB[lane][16 + r] * a1r[r];
    }

    const float linv = 1.0f / l_;
    float lrr[16];
#pragma unroll
    for (int r = 0; r < 16; ++r)
        lrr[r] = __shfl(linv, (r & 3) + 8 * (r >> 2) + 4 * hi);
    const int b = bh >> 4, h = bh & 15;
#pragma unroll
    for (int r = 0; r < 16; ++r) {
        const int q = wq0 + (r & 3) + 8 * (r >> 2) + 4 * hi;
        u16* o = &CTX[(size_t)(b * S_ + q) * D_ + h * HD_ + lo];
        o[0]  = f2bf(acc[0][r] * lrr[r]);
        o[32] = f2bf(acc[1][r] * lrr[r]);
    }
}

// ---------------------------------------------------------------------------
extern "C" void kernel_launch(void* const* d_in, const int* in_sizes, int n_in,
                              void* d_out, int out_size, void* d_ws, size_t ws_size,
                              hipStream_t stream)
{
    const float* x  = (const float*)d_in[0];
    const float* wq = (const float*)d_in[1];
    const float* bq = (const float*)d_in[2];
    const float* wk = (const float*)d_in[3];
    const float* bk = (const float*)d_in[4];
    const float* wv = (const float*)d_in[5];
    const float* bv = (const float*)d_in[6];
    const float* wo = (const float*)d_in[7];
    const float* bo = (const float*)d_in[8];

    char* ws = (char*)d_ws;
    u16*   xb    = (u16*)ws;                                  // 8 MB (reused as ctx)
    u16*   WtAll = (u16*)(ws + (size_t)8  * 1024 * 1024);     // 8 MB, rows q|k|v|o
    u16*   qkv   = (u16*)(ws + (size_t)16 * 1024 * 1024);     // 24 MB: q | k | vT
    u16*   ctx   = xb;

    cvt_fused<<<3072, 256, 0, stream>>>(x, xb, wq, wk, wv, wo, WtAll);

    gemm2<128, 0><<<dim3(24, 32), 256, 0, stream>>>(xb, WtAll, bq, bk, bv, qkv);

    attn16<<<dim3(2048), 128, 0, stream>>>(qkv, qkv + NEL, qkv + 2 * (size_t)NEL, ctx);

    // O-projection: BM=64 (r19 measured optimum; r20 falsified BM=128 here)
    gemm2<64, 1><<<dim3(8, 64), 256, 0, stream>>>(ctx, WtAll + (size_t)3072 * K_,
                                                  bo, bo, bo, d_out);
}